// Round 1
// baseline (1679.456 us; speedup 1.0000x reference)
//
#include <hip/hip_runtime.h>
#include <hip/hip_bf16.h>
#include <stdint.h>

#define E_ 8
#define B_ 4096
#define D_ 2048
#define T_ 2048
#define H_ 2048
#define KDIM 2048
#define NDIM 2048

typedef __attribute__((ext_vector_type(4))) float f32x4;
typedef __attribute__((ext_vector_type(8))) unsigned short u16x8;
typedef __attribute__((ext_vector_type(8))) __bf16 bf16x8;

__device__ __forceinline__ unsigned short f2bf(float f) {
    __hip_bfloat16 h = __float2bfloat16(f);
    return __builtin_bit_cast(unsigned short, h);
}

// ---------------------------------------------------------------------------
// Gating: logits[b,e] = xs[e,b,:] . Wg + bg  (f32, exact ranking),
// softmax over E=8, top-2, append slots to per-expert lists.
// ---------------------------------------------------------------------------
__global__ __launch_bounds__(256) void moe_gating(
    const float* __restrict__ xs, const float* __restrict__ Wg,
    const float* __restrict__ bg, float* __restrict__ out_topk,
    float* __restrict__ prob_slot, int* __restrict__ counts,
    int* __restrict__ slot_of)
{
    const int b = blockIdx.x;
    const int t = threadIdx.x;
    const int wave = t >> 6, lane = t & 63;
    __shared__ float red[E_][4];

    const f32x4 wg0 = ((const f32x4*)Wg)[t];
    const f32x4 wg1 = ((const f32x4*)Wg)[t + 256];

    for (int e = 0; e < E_; ++e) {
        const f32x4* xr = (const f32x4*)(xs + ((size_t)e * B_ + b) * D_);
        f32x4 a0 = xr[t], a1 = xr[t + 256];
        float p = a0.x*wg0.x + a0.y*wg0.y + a0.z*wg0.z + a0.w*wg0.w
                + a1.x*wg1.x + a1.y*wg1.y + a1.z*wg1.z + a1.w*wg1.w;
        #pragma unroll
        for (int off = 32; off >= 1; off >>= 1) p += __shfl_xor(p, off);
        if (lane == 0) red[e][wave] = p;
    }
    __syncthreads();
    if (t == 0) {
        float pr[E_];
        float mx = -3.0e38f;
        #pragma unroll
        for (int e = 0; e < E_; ++e) {
            pr[e] = red[e][0] + red[e][1] + red[e][2] + red[e][3] + bg[0];
            mx = fmaxf(mx, pr[e]);
        }
        float s = 0.f;
        #pragma unroll
        for (int e = 0; e < E_; ++e) { pr[e] = expf(pr[e] - mx); s += pr[e]; }
        float inv = 1.0f / s;
        #pragma unroll
        for (int e = 0; e < E_; ++e) pr[e] *= inv;
        // top-2 (strict > keeps lowest index on ties, matching jax.lax.top_k)
        int i0 = 0;
        #pragma unroll
        for (int e = 1; e < E_; ++e) if (pr[e] > pr[i0]) i0 = e;
        int i1 = (i0 == 0) ? 1 : 0;
        #pragma unroll
        for (int e = 0; e < E_; ++e) { if (e != i0 && pr[e] > pr[i1]) i1 = e; }
        float p0 = pr[i0], p1 = pr[i1];
        out_topk[2*b]   = p0;
        out_topk[2*b+1] = p1;
        prob_slot[2*b]   = p0;
        prob_slot[2*b+1] = p1;
        int pos0 = atomicAdd(&counts[i0], 1);
        slot_of[i0 * B_ + pos0] = 2*b;
        int pos1 = atomicAdd(&counts[i1], 1);
        slot_of[i1 * B_ + pos1] = 2*b + 1;
    }
}

// ---------------------------------------------------------------------------
// Expert GEMM, 128x128 tile, BK=64, 4 waves (2x2), mfma_f32_16x16x32_bf16.
// A tile and B^T tile both stored [row][k] bf16 in LDS, XOR-swizzled
// (kblk ^= row&7) so ds_read_b128 fragment reads are bank-conflict-free.
// LAYER 1: A = gathered xs rows (f32->bf16), epi = relu(acc+b1) -> hidden.
// LAYER 2: A = gathered hidden rows (bf16),  epi = atomicAdd(p*(acc+b2)).
// ---------------------------------------------------------------------------
template<int LAYER>
__global__ __launch_bounds__(256) void moe_gemm(
    const float* __restrict__ xs,
    const unsigned short* __restrict__ hidden_in,
    const float* __restrict__ W,
    const float* __restrict__ bias,
    const int* __restrict__ counts,
    const int* __restrict__ slot_of,
    const float* __restrict__ prob_slot,
    unsigned short* __restrict__ hidden_out,
    float* __restrict__ out)
{
    const int e   = blockIdx.z;
    const int n_e = counts[e];
    const int m0  = blockIdx.x * 128;
    if (m0 >= n_e) return;
    const int n0  = blockIdx.y * 128;
    const int t    = threadIdx.x;
    const int lane = t & 63;
    const int wave = t >> 6;
    const int wm = (wave >> 1) * 64;
    const int wn = (wave & 1) * 64;

    __shared__ u16x8 As[1024];   // [128 rows][8 kblks of 8 bf16], swizzled
    __shared__ u16x8 Bs[1024];
    __shared__ int   slots_s[128];
    __shared__ float probs_s[128];

    if (t < 128) {
        int gm = m0 + t;
        int s = -1; float p = 0.f;
        if (gm < n_e) { s = slot_of[e * B_ + gm]; p = prob_slot[s]; }
        slots_s[t] = s;
        probs_s[t] = p;
    }
    __syncthreads();

    f32x4 acc[4][4];
    #pragma unroll
    for (int i = 0; i < 4; ++i)
        #pragma unroll
        for (int j = 0; j < 4; ++j) {
            f32x4 z = {0.f, 0.f, 0.f, 0.f};
            acc[i][j] = z;
        }

    // A staging assignment: 2 threads per row, 32 k each
    const int ar  = t & 127;
    const int akh = t >> 7;            // 0/1 -> k-half
    const int sA  = slots_s[ar];

    // B staging assignment: thread covers 4 n-rows x 8 k (one kblk)
    const int bn4 = (t & 31) * 4;
    const int bkb = t >> 5;            // kblk 0..7
    const float* Wp = W + (size_t)e * KDIM * NDIM + n0;

    for (int k0 = 0; k0 < KDIM; k0 += 64) {
        // ---- stage A ----
        if (LAYER == 1) {
            const f32x4* src = (const f32x4*)(xs);
            if (sA >= 0)
                src = (const f32x4*)(xs + ((size_t)e * B_ + (sA >> 1)) * D_ + k0 + akh * 32);
            #pragma unroll
            for (int i = 0; i < 4; ++i) {
                u16x8 w;
                #pragma unroll
                for (int j = 0; j < 8; ++j) w[j] = 0;
                if (sA >= 0) {
                    f32x4 v0 = src[2*i], v1 = src[2*i + 1];
                    w[0]=f2bf(v0.x); w[1]=f2bf(v0.y); w[2]=f2bf(v0.z); w[3]=f2bf(v0.w);
                    w[4]=f2bf(v1.x); w[5]=f2bf(v1.y); w[6]=f2bf(v1.z); w[7]=f2bf(v1.w);
                }
                int kblk = akh * 4 + i;
                As[ar * 8 + (kblk ^ (ar & 7))] = w;
            }
        } else {
            const u16x8* src = (const u16x8*)(hidden_in);
            if (sA >= 0)
                src = (const u16x8*)(hidden_in + (size_t)sA * H_ + k0 + akh * 32);
            #pragma unroll
            for (int i = 0; i < 4; ++i) {
                u16x8 w;
                #pragma unroll
                for (int j = 0; j < 8; ++j) w[j] = 0;
                if (sA >= 0) w = src[i];
                int kblk = akh * 4 + i;
                As[ar * 8 + (kblk ^ (ar & 7))] = w;
            }
        }
        // ---- stage B (transpose-convert from W[k][n]) ----
        {
            f32x4 colv[8];
            #pragma unroll
            for (int j = 0; j < 8; ++j)
                colv[j] = *(const f32x4*)(Wp + (size_t)(k0 + bkb * 8 + j) * NDIM + bn4);
            #pragma unroll
            for (int i = 0; i < 4; ++i) {
                u16x8 w;
                #pragma unroll
                for (int j = 0; j < 8; ++j) w[j] = f2bf(colv[j][i]);
                int row = bn4 + i;
                Bs[row * 8 + (bkb ^ (row & 7))] = w;
            }
        }
        __syncthreads();

        // ---- compute: 2 x (8 ds_read_b128 + 16 MFMA) per wave ----
        #pragma unroll
        for (int kk = 0; kk < 2; ++kk) {
            const int kb = kk * 4 + (lane >> 4);
            bf16x8 af[4], bq[4];
            #pragma unroll
            for (int mi = 0; mi < 4; ++mi) {
                int row = wm + mi * 16 + (lane & 15);
                af[mi] = __builtin_bit_cast(bf16x8, As[row * 8 + (kb ^ (row & 7))]);
            }
            #pragma unroll
            for (int ni = 0; ni < 4; ++ni) {
                int row = wn + ni * 16 + (lane & 15);
                bq[ni] = __builtin_bit_cast(bf16x8, Bs[row * 8 + (kb ^ (row & 7))]);
            }
            #pragma unroll
            for (int mi = 0; mi < 4; ++mi)
                #pragma unroll
                for (int ni = 0; ni < 4; ++ni)
                    acc[mi][ni] = __builtin_amdgcn_mfma_f32_16x16x32_bf16(
                        af[mi], bq[ni], acc[mi][ni], 0, 0, 0);
        }
        __syncthreads();
    }

    // ---- epilogue ----
    // C/D layout (m89-verified): col = lane&15, row = (lane>>4)*4 + reg
    #pragma unroll
    for (int mi = 0; mi < 4; ++mi) {
        #pragma unroll
        for (int rr = 0; rr < 4; ++rr) {
            const int rloc = wm + mi * 16 + ((lane >> 4) << 2) + rr;
            const int s = slots_s[rloc];
            if (s < 0) continue;
            #pragma unroll
            for (int ni = 0; ni < 4; ++ni) {
                const int col = n0 + wn + ni * 16 + (lane & 15);
                float v = acc[mi][ni][rr];
                if (LAYER == 1) {
                    v += bias[e * NDIM + col];
                    v = fmaxf(v, 0.f);
                    hidden_out[(size_t)s * H_ + col] = f2bf(v);
                } else {
                    v = (v + bias[e * NDIM + col]) * probs_s[rloc];
                    atomicAdd(&out[(size_t)(s >> 1) * T_ + col], v);
                }
            }
        }
    }
}

// ---------------------------------------------------------------------------
// ws layout:
//   [0,256)                     int counts[8] (padded)
//   [256, 256+E*B*4)            int slot_of[E][B]
//   [.., +2*B*4)                float prob_slot[B*2]
//   [164096, +B*2*H*2)          bf16 hidden[B*2][H]   (33.55 MB)
// total ~33.7 MB
// ---------------------------------------------------------------------------
extern "C" void kernel_launch(void* const* d_in, const int* in_sizes, int n_in,
                              void* d_out, int out_size, void* d_ws, size_t ws_size,
                              hipStream_t stream)
{
    const float* xs = (const float*)d_in[0];
    const float* Wg = (const float*)d_in[1];
    const float* bg = (const float*)d_in[2];
    const float* W1 = (const float*)d_in[3];
    const float* b1 = (const float*)d_in[4];
    const float* W2 = (const float*)d_in[5];
    const float* b2 = (const float*)d_in[6];

    float* out      = (float*)d_out;
    float* out_topk = out + (size_t)B_ * T_;

    char* ws = (char*)d_ws;
    int*   counts    = (int*)ws;
    int*   slot_of   = (int*)(ws + 256);
    float* prob_slot = (float*)(ws + 256 + E_ * B_ * 4);
    unsigned short* hidden =
        (unsigned short*)(ws + 256 + E_ * B_ * 4 + 2 * B_ * 4);

    hipMemsetAsync(counts, 0, 256, stream);
    hipMemsetAsync(out, 0, (size_t)B_ * T_ * sizeof(float), stream);

    moe_gating<<<dim3(B_), dim3(256), 0, stream>>>(
        xs, Wg, bg, out_topk, prob_slot, counts, slot_of);

    dim3 grid(32, 16, E_), blk(256);
    moe_gemm<1><<<grid, blk, 0, stream>>>(
        xs, nullptr, W1, b1, counts, slot_of, prob_slot, hidden, nullptr);
    moe_gemm<2><<<grid, blk, 0, stream>>>(
        nullptr, hidden, W2, b2, counts, slot_of, prob_slot, nullptr, out);
}

// Round 2
// 1107.073 us; speedup vs baseline: 1.5170x; 1.5170x over previous
//
#include <hip/hip_runtime.h>
#include <hip/hip_bf16.h>
#include <stdint.h>

#define E_ 8
#define B_ 4096
#define D_ 2048
#define T_ 2048
#define H_ 2048
#define KDIM 2048
#define NDIM 2048

typedef __attribute__((ext_vector_type(4))) float f32x4;
typedef __attribute__((ext_vector_type(8))) unsigned short u16x8;
typedef __attribute__((ext_vector_type(8))) __bf16 bf16x8;

__device__ __forceinline__ unsigned short f2bf(float f) {
    __hip_bfloat16 h = __float2bfloat16(f);
    return __builtin_bit_cast(unsigned short, h);
}

__device__ __forceinline__ void gload_lds16(const void* g, void* lds) {
    __builtin_amdgcn_global_load_lds(
        (const __attribute__((address_space(1))) void*)g,
        (__attribute__((address_space(3))) void*)lds, 16, 0, 0);
}

// ---------------------------------------------------------------------------
// Gating: f32 logits (exact ranking), softmax, top-2, per-expert slot lists.
// Also packs the 2 selected xs rows (L2-hot) to bf16 A1[slot][D].
// ---------------------------------------------------------------------------
__global__ __launch_bounds__(256) void moe_gating(
    const float* __restrict__ xs, const float* __restrict__ Wg,
    const float* __restrict__ bg, float* __restrict__ out_topk,
    float* __restrict__ prob_slot, int* __restrict__ counts,
    int* __restrict__ slot_of, unsigned short* __restrict__ A1)
{
    const int b = blockIdx.x;
    const int t = threadIdx.x;
    const int wave = t >> 6, lane = t & 63;
    __shared__ float red[E_][4];
    __shared__ int sh_i0, sh_i1;

    const f32x4 wg0 = ((const f32x4*)Wg)[t];
    const f32x4 wg1 = ((const f32x4*)Wg)[t + 256];

    for (int e = 0; e < E_; ++e) {
        const f32x4* xr = (const f32x4*)(xs + ((size_t)e * B_ + b) * D_);
        f32x4 a0 = xr[t], a1 = xr[t + 256];
        float p = a0.x*wg0.x + a0.y*wg0.y + a0.z*wg0.z + a0.w*wg0.w
                + a1.x*wg1.x + a1.y*wg1.y + a1.z*wg1.z + a1.w*wg1.w;
        #pragma unroll
        for (int off = 32; off >= 1; off >>= 1) p += __shfl_xor(p, off);
        if (lane == 0) red[e][wave] = p;
    }
    __syncthreads();
    if (t == 0) {
        float pr[E_];
        float mx = -3.0e38f;
        #pragma unroll
        for (int e = 0; e < E_; ++e) {
            pr[e] = red[e][0] + red[e][1] + red[e][2] + red[e][3] + bg[0];
            mx = fmaxf(mx, pr[e]);
        }
        float s = 0.f;
        #pragma unroll
        for (int e = 0; e < E_; ++e) { pr[e] = expf(pr[e] - mx); s += pr[e]; }
        float inv = 1.0f / s;
        #pragma unroll
        for (int e = 0; e < E_; ++e) pr[e] *= inv;
        int i0 = 0;
        #pragma unroll
        for (int e = 1; e < E_; ++e) if (pr[e] > pr[i0]) i0 = e;
        int i1 = (i0 == 0) ? 1 : 0;
        #pragma unroll
        for (int e = 0; e < E_; ++e) { if (e != i0 && pr[e] > pr[i1]) i1 = e; }
        float p0 = pr[i0], p1 = pr[i1];
        out_topk[2*b]    = p0;
        out_topk[2*b+1]  = p1;
        prob_slot[2*b]   = p0;
        prob_slot[2*b+1] = p1;
        int pos0 = atomicAdd(&counts[i0], 1);
        slot_of[i0 * B_ + pos0] = 2*b;
        int pos1 = atomicAdd(&counts[i1], 1);
        slot_of[i1 * B_ + pos1] = 2*b + 1;
        sh_i0 = i0; sh_i1 = i1;
    }
    __syncthreads();
    const int i0 = sh_i0, i1 = sh_i1;
    // pack selected rows -> bf16 A1 (slot-indexed)
    {
        const f32x4* r0 = (const f32x4*)(xs + ((size_t)i0 * B_ + b) * D_);
        f32x4 v0 = r0[2*t], v1 = r0[2*t+1];
        u16x8 w;
        w[0]=f2bf(v0.x); w[1]=f2bf(v0.y); w[2]=f2bf(v0.z); w[3]=f2bf(v0.w);
        w[4]=f2bf(v1.x); w[5]=f2bf(v1.y); w[6]=f2bf(v1.z); w[7]=f2bf(v1.w);
        ((u16x8*)(A1 + (size_t)(2*b) * D_))[t] = w;
    }
    {
        const f32x4* r1 = (const f32x4*)(xs + ((size_t)i1 * B_ + b) * D_);
        f32x4 v0 = r1[2*t], v1 = r1[2*t+1];
        u16x8 w;
        w[0]=f2bf(v0.x); w[1]=f2bf(v0.y); w[2]=f2bf(v0.z); w[3]=f2bf(v0.w);
        w[4]=f2bf(v1.x); w[5]=f2bf(v1.y); w[6]=f2bf(v1.z); w[7]=f2bf(v1.w);
        ((u16x8*)(A1 + (size_t)(2*b+1) * D_))[t] = w;
    }
}

// ---------------------------------------------------------------------------
// Weight transpose-convert: W[e][K][N] f32 -> Wt[e][N][K] bf16, 64x64 tiles.
// ---------------------------------------------------------------------------
__global__ __launch_bounds__(256) void wtrans(
    const float* __restrict__ W, unsigned short* __restrict__ Wt)
{
    const int e  = blockIdx.z;
    const int kb = blockIdx.x * 64;
    const int nb = blockIdx.y * 64;
    const int t  = threadIdx.x;
    __shared__ float tile[64][68];   // stride 68 keeps f32x4 stores 16B-aligned

    const float* src = W + ((size_t)e * KDIM + kb) * NDIM + nb;
    {
        const int kr = t >> 2, nc = (t & 3) * 16;
        #pragma unroll
        for (int j = 0; j < 4; ++j) {
            f32x4 v = *(const f32x4*)(src + (size_t)kr * NDIM + nc + j * 4);
            *(f32x4*)&tile[kr][nc + j * 4] = v;
        }
    }
    __syncthreads();
    {
        const int nn = t >> 2, kc = (t & 3) * 16;
        unsigned short wbuf[16];
        #pragma unroll
        for (int j = 0; j < 16; ++j) wbuf[j] = f2bf(tile[kc + j][nn]);
        unsigned short* dst = Wt + ((size_t)e * NDIM + nb + nn) * KDIM + kb + kc;
        *(u16x8*)dst       = *(const u16x8*)&wbuf[0];
        *((u16x8*)dst + 1) = *(const u16x8*)&wbuf[8];
    }
}

// ---------------------------------------------------------------------------
// Expert GEMM, m97 structure: 128x128 tile, BK=64, 4 waves, bf16 MFMA,
// global_load_lds(16B) with pre-swizzled global source (kblk ^= row&7),
// linear LDS dest, swizzled ds_read_b128 fragment reads.
// A is slot-indexed bf16 (A1 or hidden), B is Wt[e][n][k] bf16.
// ---------------------------------------------------------------------------
template<int LAYER>
__global__ __launch_bounds__(256) void moe_gemm(
    const unsigned short* __restrict__ Abuf,
    const unsigned short* __restrict__ Wt,
    const float* __restrict__ bias,
    const int* __restrict__ counts,
    const int* __restrict__ slot_of,
    const float* __restrict__ prob_slot,
    unsigned short* __restrict__ hidden_out,
    float* __restrict__ out)
{
    const int e   = blockIdx.z;
    const int n_e = counts[e];
    const int m0  = blockIdx.x * 128;
    if (m0 >= n_e) return;
    const int n0  = blockIdx.y * 128;
    const int t    = threadIdx.x;
    const int lane = t & 63;
    const int wave = t >> 6;
    const int wm = (wave >> 1) * 64;
    const int wn = (wave & 1) * 64;

    __shared__ u16x8 As[1024];   // [128 rows][8 x 16B], swizzled content
    __shared__ u16x8 Bs[1024];
    __shared__ int   slots_s[128];
    __shared__ float probs_s[128];

    if (t < 128) {
        int gm = m0 + t;
        int s = -1; float p = 0.f;
        if (gm < n_e) { s = slot_of[e * B_ + gm]; p = prob_slot[s]; }
        slots_s[t] = s;
        probs_s[t] = p;
    }
    __syncthreads();

    // staging: thread t covers LDS 16B-units {t + i*256}; unit u -> row u>>3,
    // kblk-slot u&7; source kblk = slot ^ (row&7)  (inverse swizzle, rule #21)
    const int kSrc = (((t & 7) ^ ((t >> 3) & 7)) << 3);   // bf16 elems
    const unsigned short* aSrc[4];
    const unsigned short* bSrc[4];
    #pragma unroll
    for (int i = 0; i < 4; ++i) {
        const int r = i * 32 + (t >> 3);
        int s = slots_s[r]; if (s < 0) s = 0;
        aSrc[i] = Abuf + (size_t)s * KDIM + kSrc;
        bSrc[i] = Wt + ((size_t)e * NDIM + n0 + r) * KDIM + kSrc;
    }
    u16x8* aDst = &As[wave * 64];
    u16x8* bDst = &Bs[wave * 64];

    f32x4 acc[4][4];
    #pragma unroll
    for (int i = 0; i < 4; ++i)
        #pragma unroll
        for (int j = 0; j < 4; ++j) {
            f32x4 z = {0.f, 0.f, 0.f, 0.f};
            acc[i][j] = z;
        }

    for (int k0 = 0; k0 < KDIM; k0 += 64) {
        #pragma unroll
        for (int i = 0; i < 4; ++i) gload_lds16(aSrc[i] + k0, aDst + i * 256);
        #pragma unroll
        for (int i = 0; i < 4; ++i) gload_lds16(bSrc[i] + k0, bDst + i * 256);
        __syncthreads();

        #pragma unroll
        for (int kk = 0; kk < 2; ++kk) {
            const int kb = kk * 4 + (lane >> 4);
            bf16x8 af[4], bq[4];
            #pragma unroll
            for (int mi = 0; mi < 4; ++mi) {
                const int row = wm + mi * 16 + (lane & 15);
                af[mi] = __builtin_bit_cast(bf16x8, As[row * 8 + (kb ^ (row & 7))]);
            }
            #pragma unroll
            for (int ni = 0; ni < 4; ++ni) {
                const int row = wn + ni * 16 + (lane & 15);
                bq[ni] = __builtin_bit_cast(bf16x8, Bs[row * 8 + (kb ^ (row & 7))]);
            }
            #pragma unroll
            for (int mi = 0; mi < 4; ++mi)
                #pragma unroll
                for (int ni = 0; ni < 4; ++ni)
                    acc[mi][ni] = __builtin_amdgcn_mfma_f32_16x16x32_bf16(
                        af[mi], bq[ni], acc[mi][ni], 0, 0, 0);
        }
        __syncthreads();
    }

    // epilogue — C/D layout: col = lane&15, row = (lane>>4)*4 + reg
    #pragma unroll
    for (int mi = 0; mi < 4; ++mi) {
        #pragma unroll
        for (int rr = 0; rr < 4; ++rr) {
            const int rloc = wm + mi * 16 + ((lane >> 4) << 2) + rr;
            const int s = slots_s[rloc];
            if (s < 0) continue;
            #pragma unroll
            for (int ni = 0; ni < 4; ++ni) {
                const int col = n0 + wn + ni * 16 + (lane & 15);
                float v = acc[mi][ni][rr];
                if (LAYER == 1) {
                    v += bias[e * NDIM + col];
                    v = fmaxf(v, 0.f);
                    hidden_out[(size_t)s * H_ + col] = f2bf(v);
                } else {
                    v = (v + bias[e * NDIM + col]) * probs_s[rloc];
                    atomicAdd(&out[(size_t)(s >> 1) * T_ + col], v);
                }
            }
        }
    }
}

// ---------------------------------------------------------------------------
// ws layout (~134.4 MB):
//   [0,256)           counts
//   [256,+E*B*4)      slot_of
//   [..,+2B*4)        prob_slot
//   A1    [2B][D] bf16   33.55 MB
//   hidden[2B][H] bf16   33.55 MB
//   Wt    [E][N][K] bf16 67.11 MB  (shared by both layers, stream-serialized)
// ---------------------------------------------------------------------------
extern "C" void kernel_launch(void* const* d_in, const int* in_sizes, int n_in,
                              void* d_out, int out_size, void* d_ws, size_t ws_size,
                              hipStream_t stream)
{
    const float* xs = (const float*)d_in[0];
    const float* Wg = (const float*)d_in[1];
    const float* bg = (const float*)d_in[2];
    const float* W1 = (const float*)d_in[3];
    const float* b1 = (const float*)d_in[4];
    const float* W2 = (const float*)d_in[5];
    const float* b2 = (const float*)d_in[6];

    float* out      = (float*)d_out;
    float* out_topk = out + (size_t)B_ * T_;

    char* ws = (char*)d_ws;
    int*   counts    = (int*)ws;
    int*   slot_of   = (int*)(ws + 256);
    float* prob_slot = (float*)(ws + 256 + E_ * B_ * 4);
    size_t off = 256 + (size_t)E_ * B_ * 4 + 2 * B_ * 4;
    off = (off + 255) & ~(size_t)255;
    unsigned short* A1     = (unsigned short*)(ws + off); off += (size_t)2 * B_ * D_ * 2;
    unsigned short* hidden = (unsigned short*)(ws + off); off += (size_t)2 * B_ * H_ * 2;
    unsigned short* Wtb    = (unsigned short*)(ws + off);

    hipMemsetAsync(counts, 0, 256, stream);
    hipMemsetAsync(out, 0, (size_t)B_ * T_ * sizeof(float), stream);

    moe_gating<<<dim3(B_), dim3(256), 0, stream>>>(
        xs, Wg, bg, out_topk, prob_slot, counts, slot_of, A1);

    dim3 tgrid(32, 32, E_), grid(32, 16, E_), blk(256);

    wtrans<<<tgrid, blk, 0, stream>>>(W1, Wtb);
    moe_gemm<1><<<grid, blk, 0, stream>>>(
        A1, Wtb, b1, counts, slot_of, prob_slot, hidden, nullptr);

    wtrans<<<tgrid, blk, 0, stream>>>(W2, Wtb);
    moe_gemm<2><<<grid, blk, 0, stream>>>(
        hidden, Wtb, b2, counts, slot_of, prob_slot, nullptr, out);
}

// Round 3
// 571.402 us; speedup vs baseline: 2.9392x; 1.9375x over previous
//
#include <hip/hip_runtime.h>
#include <hip/hip_bf16.h>
#include <stdint.h>

#define E_ 8
#define B_ 4096
#define D_ 2048
#define T_ 2048
#define H_ 2048
#define KDIM 2048
#define NDIM 2048

typedef __attribute__((ext_vector_type(4))) float f32x4;
typedef __attribute__((ext_vector_type(8))) unsigned short u16x8;
typedef __attribute__((ext_vector_type(8))) __bf16 bf16x8;

__device__ __forceinline__ unsigned short f2bf(float f) {
    __hip_bfloat16 h = __float2bfloat16(f);
    return __builtin_bit_cast(unsigned short, h);
}

__device__ __forceinline__ void gload_lds16(const void* g, void* lds) {
    __builtin_amdgcn_global_load_lds(
        (const __attribute__((address_space(1))) void*)g,
        (__attribute__((address_space(3))) void*)lds, 16, 0, 0);
}

// ---------------------------------------------------------------------------
// Gating: f32 logits (exact ranking), softmax, top-2, per-expert slot lists.
// Also packs the 2 selected xs rows (L2-hot) to bf16 A1[slot][D].
// ---------------------------------------------------------------------------
__global__ __launch_bounds__(256) void moe_gating(
    const float* __restrict__ xs, const float* __restrict__ Wg,
    const float* __restrict__ bg, float* __restrict__ out_topk,
    float* __restrict__ prob_slot, int* __restrict__ counts,
    int* __restrict__ slot_of, unsigned short* __restrict__ A1)
{
    const int b = blockIdx.x;
    const int t = threadIdx.x;
    const int wave = t >> 6, lane = t & 63;
    __shared__ float red[E_][4];
    __shared__ int sh_i0, sh_i1;

    const f32x4 wg0 = ((const f32x4*)Wg)[t];
    const f32x4 wg1 = ((const f32x4*)Wg)[t + 256];

    for (int e = 0; e < E_; ++e) {
        const f32x4* xr = (const f32x4*)(xs + ((size_t)e * B_ + b) * D_);
        f32x4 a0 = xr[t], a1 = xr[t + 256];
        float p = a0.x*wg0.x + a0.y*wg0.y + a0.z*wg0.z + a0.w*wg0.w
                + a1.x*wg1.x + a1.y*wg1.y + a1.z*wg1.z + a1.w*wg1.w;
        #pragma unroll
        for (int off = 32; off >= 1; off >>= 1) p += __shfl_xor(p, off);
        if (lane == 0) red[e][wave] = p;
    }
    __syncthreads();
    if (t == 0) {
        float pr[E_];
        float mx = -3.0e38f;
        #pragma unroll
        for (int e = 0; e < E_; ++e) {
            pr[e] = red[e][0] + red[e][1] + red[e][2] + red[e][3] + bg[0];
            mx = fmaxf(mx, pr[e]);
        }
        float s = 0.f;
        #pragma unroll
        for (int e = 0; e < E_; ++e) { pr[e] = expf(pr[e] - mx); s += pr[e]; }
        float inv = 1.0f / s;
        #pragma unroll
        for (int e = 0; e < E_; ++e) pr[e] *= inv;
        int i0 = 0;
        #pragma unroll
        for (int e = 1; e < E_; ++e) if (pr[e] > pr[i0]) i0 = e;
        int i1 = (i0 == 0) ? 1 : 0;
        #pragma unroll
        for (int e = 0; e < E_; ++e) { if (e != i0 && pr[e] > pr[i1]) i1 = e; }
        float p0 = pr[i0], p1 = pr[i1];
        out_topk[2*b]    = p0;
        out_topk[2*b+1]  = p1;
        prob_slot[2*b]   = p0;
        prob_slot[2*b+1] = p1;
        int pos0 = atomicAdd(&counts[i0], 1);
        slot_of[i0 * B_ + pos0] = 2*b;
        int pos1 = atomicAdd(&counts[i1], 1);
        slot_of[i1 * B_ + pos1] = 2*b + 1;
        sh_i0 = i0; sh_i1 = i1;
    }
    __syncthreads();
    const int i0 = sh_i0, i1 = sh_i1;
    {
        const f32x4* r0 = (const f32x4*)(xs + ((size_t)i0 * B_ + b) * D_);
        f32x4 v0 = r0[2*t], v1 = r0[2*t+1];
        u16x8 w;
        w[0]=f2bf(v0.x); w[1]=f2bf(v0.y); w[2]=f2bf(v0.z); w[3]=f2bf(v0.w);
        w[4]=f2bf(v1.x); w[5]=f2bf(v1.y); w[6]=f2bf(v1.z); w[7]=f2bf(v1.w);
        ((u16x8*)(A1 + (size_t)(2*b) * D_))[t] = w;
    }
    {
        const f32x4* r1 = (const f32x4*)(xs + ((size_t)i1 * B_ + b) * D_);
        f32x4 v0 = r1[2*t], v1 = r1[2*t+1];
        u16x8 w;
        w[0]=f2bf(v0.x); w[1]=f2bf(v0.y); w[2]=f2bf(v0.z); w[3]=f2bf(v0.w);
        w[4]=f2bf(v1.x); w[5]=f2bf(v1.y); w[6]=f2bf(v1.z); w[7]=f2bf(v1.w);
        ((u16x8*)(A1 + (size_t)(2*b+1) * D_))[t] = w;
    }
}

// ---------------------------------------------------------------------------
// Build compact (expert, m-tile) work list. Max Sum(ceil(n_e/256)) = 39.
// ---------------------------------------------------------------------------
__global__ void build_tiles(const int* __restrict__ counts, int* __restrict__ tiles)
{
    if (threadIdx.x == 0 && blockIdx.x == 0) {
        int n = 0;
        for (int e = 0; e < E_; ++e) {
            int te = (counts[e] + 255) >> 8;
            for (int m = 0; m < te; ++m) tiles[1 + n++] = (e << 16) | m;
        }
        tiles[0] = n;
    }
}

// ---------------------------------------------------------------------------
// Weight transpose-convert: W[e][K][N] f32 -> Wt[e][N][K] bf16, 64x64 tiles.
// ---------------------------------------------------------------------------
__global__ __launch_bounds__(256) void wtrans(
    const float* __restrict__ W, unsigned short* __restrict__ Wt)
{
    const int e  = blockIdx.z;
    const int kb = blockIdx.x * 64;
    const int nb = blockIdx.y * 64;
    const int t  = threadIdx.x;
    __shared__ float tile[64][68];

    const float* src = W + ((size_t)e * KDIM + kb) * NDIM + nb;
    {
        const int kr = t >> 2, nc = (t & 3) * 16;
        #pragma unroll
        for (int j = 0; j < 4; ++j) {
            f32x4 v = *(const f32x4*)(src + (size_t)kr * NDIM + nc + j * 4);
            *(f32x4*)&tile[kr][nc + j * 4] = v;
        }
    }
    __syncthreads();
    {
        const int nn = t >> 2, kc = (t & 3) * 16;
        unsigned short wbuf[16];
        #pragma unroll
        for (int j = 0; j < 16; ++j) wbuf[j] = f2bf(tile[kc + j][nn]);
        unsigned short* dst = Wt + ((size_t)e * NDIM + nb + nn) * KDIM + kb + kc;
        *(u16x8*)dst       = *(const u16x8*)&wbuf[0];
        *((u16x8*)dst + 1) = *(const u16x8*)&wbuf[8];
    }
}

// ---------------------------------------------------------------------------
// 256x256 8-phase expert GEMM (m201-style): BK=64, 8 waves (2M x 4N),
// 128 KiB dbuf LDS, global_load_lds(16B) w/ pre-swizzled source, counted
// vmcnt(4) at phases 0/4 only, setprio around MFMA clusters.
// Regions: A-even rows {0-63,128-191}, A-odd rest; B-even rows with bit5=0.
// Per-iter stage schedule (verified WAR/RAW):
//   p0:A1odd(2i+1) p1:A0even(2i+2) p2:B0even p3:B0odd p4:A0odd
//   p5:A1even(2i+3) p6:B1even p7:B1odd
// ---------------------------------------------------------------------------
#define BAR  __builtin_amdgcn_s_barrier()
#define WLG  asm volatile("s_waitcnt lgkmcnt(0)" ::: "memory")
#define WVM4 asm volatile("s_waitcnt vmcnt(4)" ::: "memory")
#define PRIO1 __builtin_amdgcn_s_setprio(1)
#define PRIO0 __builtin_amdgcn_s_setprio(0)

#define STA(BUF,P,KT) do{ \
    gload_lds16(aptr[P][0] + (KT)*64, &As[(BUF)*2048 + 0*1024 + (P)*512 + w64]); \
    gload_lds16(aptr[P][1] + (KT)*64, &As[(BUF)*2048 + 1*1024 + (P)*512 + w64]); }while(0)
#define STB(BUF,P,KT) do{ \
    gload_lds16(bptr[P][0] + (KT)*64, &Bs[(BUF)*2048 + (0*2+seg_w)*512 + (P)*256 + w3x64]); \
    gload_lds16(bptr[P][1] + (KT)*64, &Bs[(BUF)*2048 + (1*2+seg_w)*512 + (P)*256 + w3x64]); }while(0)

#define RDA(BUF,MQ) do{ \
    _Pragma("unroll") \
    for (int mf2 = 0; mf2 < 4; ++mf2) { \
        int row = wm + ((MQ)*4 + mf2) * 16 + (lane & 15); \
        int base = (BUF)*2048 + row * 8; \
        af[mf2][0] = __builtin_bit_cast(bf16x8, As[base + ((0*4 + lg) ^ (row & 7))]); \
        af[mf2][1] = __builtin_bit_cast(bf16x8, As[base + ((1*4 + lg) ^ (row & 7))]); } }while(0)
#define RDB(BUF,NQ,DST) do{ \
    _Pragma("unroll") \
    for (int nf2 = 0; nf2 < 2; ++nf2) { \
        int row = wn + ((NQ)*2 + nf2) * 16 + (lane & 15); \
        int base = (BUF)*2048 + row * 8; \
        DST[nf2][0] = __builtin_bit_cast(bf16x8, Bs[base + ((0*4 + lg) ^ (row & 7))]); \
        DST[nf2][1] = __builtin_bit_cast(bf16x8, Bs[base + ((1*4 + lg) ^ (row & 7))]); } }while(0)
#define MM(MQ,NQ,BF) do{ \
    _Pragma("unroll") \
    for (int mf2 = 0; mf2 < 4; ++mf2) \
    _Pragma("unroll") \
    for (int nf2 = 0; nf2 < 2; ++nf2) \
    _Pragma("unroll") \
    for (int kk = 0; kk < 2; ++kk) \
        acc[(MQ)*4+mf2][(NQ)*2+nf2] = __builtin_amdgcn_mfma_f32_16x16x32_bf16( \
            af[mf2][kk], BF[nf2][kk], acc[(MQ)*4+mf2][(NQ)*2+nf2], 0, 0, 0); }while(0)

template<int LAYER>
__global__ __launch_bounds__(512, 2) void moe_gemm(
    const unsigned short* __restrict__ Abuf,
    const unsigned short* __restrict__ Wt,
    const float* __restrict__ bias,
    const int* __restrict__ counts,
    const int* __restrict__ tiles,
    const int* __restrict__ slot_of,
    const float* __restrict__ prob_slot,
    unsigned short* __restrict__ hidden_out,
    float* __restrict__ out)
{
    const int nt = tiles[0];
    if ((int)blockIdx.x >= nt) return;
    const int info = tiles[1 + blockIdx.x];
    const int e  = info >> 16;
    const int m0 = (info & 0xffff) * 256;
    const int n0 = blockIdx.y * 256;
    const int n_e = counts[e];

    const int t = threadIdx.x;
    const int lane = t & 63;
    const int w = t >> 6;
    const int wm = (w >> 2) * 128;
    const int wn = (w & 3) * 64;
    const int lg = lane >> 4;

    __shared__ u16x8 As[2 * 2048];
    __shared__ u16x8 Bs[2 * 2048];
    __shared__ int   slots_s[256];
    __shared__ float probs_s[256];

    if (t < 256) {
        int gm = m0 + t;
        int s = -1; float p = 0.f;
        if (gm < n_e) { s = slot_of[e * B_ + gm]; p = prob_slot[s]; }
        slots_s[t] = s; probs_s[t] = p;
    }
    __syncthreads();

    const int swz = ((lane & 7) ^ ((lane >> 3) & 7)) * 8;
    const int rlo = lane >> 3;
    const int seg_w = w >> 2;
    const int w3x64 = (w & 3) * 64;
    const int w64 = w * 64;

    const unsigned short* aptr[2][2];
    #pragma unroll
    for (int P = 0; P < 2; ++P)
        #pragma unroll
        for (int j = 0; j < 2; ++j) {
            int rA = j * 128 + P * 64 + w * 8 + rlo;
            int s = slots_s[rA]; if (s < 0) s = 0;
            aptr[P][j] = Abuf + (size_t)s * KDIM + swz;
        }
    const unsigned short* bptr[2][2];
    #pragma unroll
    for (int P = 0; P < 2; ++P)
        #pragma unroll
        for (int j = 0; j < 2; ++j) {
            int sseg = j * 2 + seg_w;
            int rB = sseg * 64 + P * 32 + (w & 3) * 8 + rlo;
            bptr[P][j] = Wt + ((size_t)e * NDIM + n0 + rB) * KDIM + swz;
        }

    f32x4 acc[8][4];
    #pragma unroll
    for (int i = 0; i < 8; ++i)
        #pragma unroll
        for (int j = 0; j < 4; ++j) {
            f32x4 z = {0.f, 0.f, 0.f, 0.f};
            acc[i][j] = z;
        }
    bf16x8 af[4][2], bfe[2][2], bfo[2][2];

    // prologue: buf0 <- tile0 (A-even,B-even,B-odd,A-odd), buf1 <- tile1 (A-even,B-even,B-odd)
    STA(0,0,0); STB(0,0,0); STB(0,1,0); STA(0,1,0);
    STA(1,0,1); STB(1,0,1); STB(1,1,1);
    asm volatile("s_waitcnt vmcnt(6)" ::: "memory");   // buf0 fully landed
    BAR;

    for (int i = 0; i < 16; ++i) {
        const int t1 = 2*i + 1;
        int t2 = 2*i + 2; if (t2 > 31) t2 = 31;
        int t3 = 2*i + 3; if (t3 > 31) t3 = 31;
        // p0
        RDA(0,0); RDB(0,0,bfe);
        STA(1,1,t1);
        WVM4; BAR; WLG; PRIO1; MM(0,0,bfe); PRIO0; BAR;
        // p1
        RDB(0,1,bfo);
        STA(0,0,t2);
        BAR; WLG; PRIO1; MM(0,1,bfo); PRIO0; BAR;
        // p2
        RDA(0,1);
        STB(0,0,t2);
        BAR; WLG; PRIO1; MM(1,0,bfe); PRIO0; BAR;
        // p3
        STB(0,1,t2);
        BAR; PRIO1; MM(1,1,bfo); PRIO0; BAR;
        // p4
        RDA(1,0); RDB(1,0,bfe);
        STA(0,1,t2);
        WVM4; BAR; WLG; PRIO1; MM(0,0,bfe); PRIO0; BAR;
        // p5
        RDB(1,1,bfo);
        STA(1,0,t3);
        BAR; WLG; PRIO1; MM(0,1,bfo); PRIO0; BAR;
        // p6
        RDA(1,1);
        STB(1,0,t3);
        BAR; WLG; PRIO1; MM(1,0,bfe); PRIO0; BAR;
        // p7
        STB(1,1,t3);
        BAR; PRIO1; MM(1,1,bfo); PRIO0; BAR;
    }
    asm volatile("s_waitcnt vmcnt(0)" ::: "memory");   // drain DMA before LDS dealloc

    // epilogue — C/D layout: col = lane&15, row = (lane>>4)*4 + reg
    #pragma unroll
    for (int mf = 0; mf < 8; ++mf) {
        #pragma unroll
        for (int rr = 0; rr < 4; ++rr) {
            const int rloc = wm + mf * 16 + ((lane >> 4) << 2) + rr;
            const int s = slots_s[rloc];
            if (s < 0) continue;
            #pragma unroll
            for (int nf = 0; nf < 4; ++nf) {
                const int col = n0 + wn + nf * 16 + (lane & 15);
                float v = acc[mf][nf][rr];
                if (LAYER == 1) {
                    v += bias[e * NDIM + col];
                    v = fmaxf(v, 0.f);
                    hidden_out[(size_t)s * H_ + col] = f2bf(v);
                } else {
                    v = (v + bias[e * NDIM + col]) * probs_s[rloc];
                    atomicAdd(&out[(size_t)(s >> 1) * T_ + col], v);
                }
            }
        }
    }
}

// ---------------------------------------------------------------------------
// ws layout: counts@0 (256B) | tiles@256 (256B) | slot_of | prob_slot |
//            A1[2B][D] bf16 | hidden[2B][H] bf16 | Wt[E][N][K] bf16
// ---------------------------------------------------------------------------
extern "C" void kernel_launch(void* const* d_in, const int* in_sizes, int n_in,
                              void* d_out, int out_size, void* d_ws, size_t ws_size,
                              hipStream_t stream)
{
    const float* xs = (const float*)d_in[0];
    const float* Wg = (const float*)d_in[1];
    const float* bg = (const float*)d_in[2];
    const float* W1 = (const float*)d_in[3];
    const float* b1 = (const float*)d_in[4];
    const float* W2 = (const float*)d_in[5];
    const float* b2 = (const float*)d_in[6];

    float* out      = (float*)d_out;
    float* out_topk = out + (size_t)B_ * T_;

    char* ws = (char*)d_ws;
    int*   counts    = (int*)ws;
    int*   tiles     = (int*)(ws + 256);
    int*   slot_of   = (int*)(ws + 512);
    float* prob_slot = (float*)(ws + 512 + E_ * B_ * 4);
    size_t off = 512 + (size_t)E_ * B_ * 4 + 2 * B_ * 4;
    off = (off + 255) & ~(size_t)255;
    unsigned short* A1     = (unsigned short*)(ws + off); off += (size_t)2 * B_ * D_ * 2;
    unsigned short* hidden = (unsigned short*)(ws + off); off += (size_t)2 * B_ * H_ * 2;
    unsigned short* Wtb    = (unsigned short*)(ws + off);

    hipMemsetAsync(counts, 0, 256, stream);
    hipMemsetAsync(out, 0, (size_t)B_ * T_ * sizeof(float), stream);

    moe_gating<<<dim3(B_), dim3(256), 0, stream>>>(
        xs, Wg, bg, out_topk, prob_slot, counts, slot_of, A1);
    build_tiles<<<dim3(1), dim3(64), 0, stream>>>(counts, tiles);

    dim3 tgrid(32, 32, E_), ggrid(40, 8), blk(256), gblk(512);

    wtrans<<<tgrid, blk, 0, stream>>>(W1, Wtb);
    moe_gemm<1><<<ggrid, gblk, 0, stream>>>(
        A1, Wtb, b1, counts, tiles, slot_of, prob_slot, hidden, nullptr);

    wtrans<<<tgrid, blk, 0, stream>>>(W2, Wtb);
    moe_gemm<2><<<ggrid, gblk, 0, stream>>>(
        hidden, Wtb, b2, counts, tiles, slot_of, prob_slot, nullptr, out);
}